// Round 4
// baseline (325.349 us; speedup 1.0000x reference)
//
#include <hip/hip_runtime.h>

// LSTM B=4096, T=512, I=1, H=64, O=1 (fp32 in/out).
// Round 18: DENSE-ROW MB=16, one block per CU (grid 256), 4 waves.
// r17 post-mortem: +-60cyc changes to cell-math chain/trans had ZERO wall
// effect -> step time is the exchange skeleton (read->MFMA->write->barrier)
// x2 multiplexed blocks. The sparse layout (row 2q=batch, odd rows zero)
// wastes half of every MFMA row / exchange / barrier on zeros: a CU burns
// two ~544cyc skeletons for 16 batches. Dense layout (row q = batch q, all
// 16 rows live) serves 16 batches with ONE skeleton: same 8 MFMA/wave-step,
// 4 cells/lane (D rows 4h0+r all live, gates still colocated per lane,
// zero shuffles). Cell work/lane doubles but r2/r3 proved >=100cyc slack.
// Est: read ~120 + MFMA ~100 + cell ~240 (r16-proven shared-rcp math,
// 24 trans = 192cyc pipe) + write/drain/barrier ~150 ~= 600-750 cyc/step
// vs 1088 today. Pre-commit: if >=233us, single-block exposure is fatal
// and the r16/r17 multiplexed config is the structural floor.
// MFMA layouts (m89-verified): A[m=lane&15][k=(lane>>4)*8+i],
// B[k=(lane>>4)*8+i][n=lane&15], D[m=(lane>>4)*4+r][n=lane&15].

#define TT   512
#define MB   16
#define HP   72            // f16 row stride (144 B): 16B-aligned
#define BUFE (16 * HP)     // one ping-pong buffer: 16 rows
#define SXP  20            // sh_x row stride (floats); mult of 4 -> float4 ok

#define L2E  1.4426950408889634f
#define L2E2 2.8853900817779268f

typedef _Float16 f16x8 __attribute__((ext_vector_type(8)));
typedef float    f32x4 __attribute__((ext_vector_type(4)));
typedef float    f32x2 __attribute__((ext_vector_type(2)));

#define MFMA16(a, b, c) __builtin_amdgcn_mfma_f32_16x16x32_f16((a), (b), (c), 0, 0, 0)

__device__ __forceinline__ float rcp_(float x)  { return __builtin_amdgcn_rcpf(x); }
__device__ __forceinline__ float exp2_(float x) { return __builtin_amdgcn_exp2f(x); }

__device__ __forceinline__ f16x8 cvt8s(const float4& u0, const float4& u1, float s) {
    f16x8 r;
    r[0] = (_Float16)(u0.x * s); r[1] = (_Float16)(u0.y * s);
    r[2] = (_Float16)(u0.z * s); r[3] = (_Float16)(u0.w * s);
    r[4] = (_Float16)(u1.x * s); r[5] = (_Float16)(u1.y * s);
    r[6] = (_Float16)(u1.z * s); r[7] = (_Float16)(u1.w * s);
    return r;
}

__global__ __launch_bounds__(256, 1) void lstm_mfma(
    const float* __restrict__ x,      // [4096, 512]
    const float* __restrict__ w_ih,   // [256]
    const float* __restrict__ w_hh,   // [256, 64]
    const float* __restrict__ b_ih,   // [256]
    const float* __restrict__ b_hh,   // [256]
    const float* __restrict__ w_out,  // [64]
    const float* __restrict__ b_out,  // [1]
    float* __restrict__ out)          // [4096]
{
    __shared__ __align__(16) float    sh_x[TT * SXP];   // [t][q], 40 KB
    __shared__ __align__(16) _Float16 hbuf[2 * BUFE];   // 4.6 KB

    const int tid = threadIdx.x;
    const int w   = tid >> 6;    // wave 0..3 (owns N-tiles {w, w+4, w+8, w+12})
    const int L   = tid & 63;
    const int l16 = L & 15;
    const int h0  = L >> 4;      // 0..3
    const int b0  = blockIdx.x * MB;
    const int j   = 16 * w + l16;  // hidden unit col owned by this lane

    // ---- stage x: sh_x[t*SXP + q] = x[b0+q][t] (coalesced) ----
    #pragma unroll
    for (int rep = 0; rep < 2; ++rep) {
        const int q = (tid >> 5) + 8 * rep;   // batch 0..15
        const int l = tid & 31;
        const float* xr = x + (size_t)(b0 + q) * TT;
        #pragma unroll
        for (int i = 0; i < TT / 32; ++i)
            sh_x[(l + 32 * i) * SXP + q] = xr[l + 32 * i];
    }
    // ---- zero both h buffers ----
    for (int i = tid; i < 2 * BUFE; i += 256) hbuf[i] = (_Float16)0.0f;

    // ---- preload W_hh fragments, exp2-prescaled ----
    const float sc[4] = {-L2E, -L2E, L2E2, -L2E};
    f16x8 Bf[4][2];
    float wihv[4], biasv[4];
    #pragma unroll
    for (int s = 0; s < 4; ++s) {
        const int n = 64 * s + j;
        #pragma unroll
        for (int kt = 0; kt < 2; ++kt) {
            const float* p = w_hh + n * 64 + kt * 32 + h0 * 8;
            float4 u0 = *(const float4*)p;
            float4 u1 = *(const float4*)(p + 4);
            Bf[s][kt] = cvt8s(u0, u1, sc[s]);
        }
        wihv[s]  = w_ih[n] * sc[s];
        biasv[s] = (b_ih[n] + b_hh[n]) * sc[s];
    }

    // A-frag: row m=l16 = batch l16, k-slots 8h0..8h0+7 (+32 chunk 1)
    const int aoff = l16 * HP + h0 * 8;
    // lane's cells: batches 4h0+r (r=0..3), unit j -> h rows 4h0+r, col j
    const int xb   = 4 * h0;               // sh_x col base
    const int wr   = 4 * h0 * HP + j;

    f32x2 cc0 = {0.0f, 0.0f};   // c-state, batches 4h0, 4h0+1 (x2log2e dom)
    f32x2 cc1 = {0.0f, 0.0f};   // c-state, batches 4h0+2, 4h0+3

    // C-operand pipeline: all 4 rows live = x*w_ih+bias for batches 4h0+r
    f32x4 ci[4];
    {
        const float4 x0 = *(const float4*)(sh_x + xb);
        #pragma unroll
        for (int s = 0; s < 4; ++s) {
            ci[s][0] = fmaf(x0.x, wihv[s], biasv[s]);
            ci[s][1] = fmaf(x0.y, wihv[s], biasv[s]);
            ci[s][2] = fmaf(x0.z, wihv[s], biasv[s]);
            ci[s][3] = fmaf(x0.w, wihv[s], biasv[s]);
        }
    }

    __syncthreads();

    auto step = [&](const _Float16* rb, _Float16* wb, int t) {
        f16x8 a0 = *(const f16x8*)(rb + aoff);
        f16x8 a1 = *(const f16x8*)(rb + aoff + 32);

        f32x4 acc[4];
        #pragma unroll
        for (int s = 0; s < 4; ++s)
            acc[s] = MFMA16(a1, Bf[s][1], MFMA16(a0, Bf[s][0], ci[s]));

        // refresh ci for t+1 in the MFMA shadow (h-independent, packed fma)
        if (t + 1 < TT) {
            const float4 xn = *(const float4*)(sh_x + (t + 1) * SXP + xb);
            const f32x2 xa = {xn.x, xn.y}, xbv = {xn.z, xn.w};
            #pragma unroll
            for (int s = 0; s < 4; ++s) {
                f32x2 ca2 = xa  * wihv[s] + biasv[s];   // v_pk_fma_f32
                f32x2 cb2 = xbv * wihv[s] + biasv[s];
                ci[s][0] = ca2[0]; ci[s][1] = ca2[1];
                ci[s][2] = cb2[0]; ci[s][3] = cb2[1];
            }
        }

        __builtin_amdgcn_s_setprio(1);

        // ---- 4 cells as two f32x2 streams, r16-proven shared-rcp math ----
        #pragma unroll
        for (int p = 0; p < 2; ++p) {
            f32x2& cc = p ? cc1 : cc0;
            const int r0 = 2 * p;
            f32x2 Ei = {exp2_(acc[0][r0]), exp2_(acc[0][r0 + 1])};
            f32x2 Ef = {exp2_(acc[1][r0]), exp2_(acc[1][r0 + 1])};
            f32x2 Eg = {exp2_(acc[2][r0]), exp2_(acc[2][r0 + 1])};
            f32x2 Eo = {exp2_(acc[3][r0]), exp2_(acc[3][r0 + 1])};
            f32x2 Di = Ei + 1.0f, Df = Ef + 1.0f, Dg = Eg + 1.0f, Do = Eo + 1.0f;

            f32x2 FG = Df * Dg, IG = Di * Dg, IF = Di * Df;
            f32x2 P  = Di * FG;
            float u  = rcp_(P[0] * P[1]);
            f32x2 inv = {u * P[1], u * P[0]};

            f32x2 si = FG * inv, sf = IG * inv;
            f32x2 tg = 1.0f - 2.0f * (IF * inv);
            cc = sf * cc + si * tg;                       // v_pk_fma_f32

            f32x2 ca = cc * L2E2;
            f32x2 Ec = {exp2_(fminf(ca[0], 30.0f)), exp2_(fminf(ca[1], 30.0f))};
            f32x2 Dc = Ec + 1.0f;
            f32x2 Q  = Do * Dc;
            float v  = rcp_(Q[0] * Q[1]);
            f32x2 iq = {v * Q[1], v * Q[0]};
            f32x2 hv = (iq * Dc) * (1.0f - 2.0f * (iq * Do));

            wb[wr + (r0)     * HP] = (_Float16)hv[0];   // batch 4h0+r0
            wb[wr + (r0 + 1) * HP] = (_Float16)hv[1];   // batch 4h0+r0+1
        }

        __builtin_amdgcn_s_setprio(0);
        __syncthreads();
    };

    for (int t = 0; t < TT; t += 2) {
        step(hbuf,        hbuf + BUFE, t);      // read buf0, write buf1
        step(hbuf + BUFE, hbuf,        t + 1);  // read buf1, write buf0
    }

    // ---- epilogue: final h in buf0; wave w reduces batches 4w..4w+3 ----
    const float wo = w_out[L];
    #pragma unroll
    for (int p = 0; p < 4; ++p) {
        const int q = 4 * w + p;
        float v = (float)hbuf[q * HP + L] * wo;
        #pragma unroll
        for (int off = 32; off; off >>= 1) v += __shfl_down(v, off);
        if (L == 0) out[b0 + q] = v + b_out[0];
    }
}

extern "C" void kernel_launch(void* const* d_in, const int* in_sizes, int n_in,
                              void* d_out, int out_size, void* d_ws, size_t ws_size,
                              hipStream_t stream) {
    const float* x     = (const float*)d_in[0];
    const float* w_ih  = (const float*)d_in[1];
    const float* w_hh  = (const float*)d_in[2];
    const float* b_ih  = (const float*)d_in[3];
    const float* b_hh  = (const float*)d_in[4];
    const float* w_out = (const float*)d_in[5];
    const float* b_out = (const float*)d_in[6];
    float* out = (float*)d_out;

    lstm_mfma<<<4096 / MB, 256, 0, stream>>>(x, w_ih, w_hh, b_ih, b_hh,
                                             w_out, b_out, out);
}

// Round 6
// 269.670 us; speedup vs baseline: 1.2065x; 1.2065x over previous
//
#include <hip/hip_runtime.h>

// LSTM B=4096, T=512, I=1, H=64, O=1 (fp32 in/out).
// Round 19-resubmit (r5 was an infra failure: container died twice, no
// signal). r17 structure (233 us steady) + MFMA DEPENDENCY SPLIT.
// Partition sweep closed: (blocks/CU x MB) = 1x16 dense 287 (r18:
// exposure fatal), 2x8 233 (best), 4x4 314 (r15), wave-local 432/629,
// flag-sync 341, transposed 375. 16 batches/CU fixed => no other splits.
// r17 proved the post-exp2 chain has >=60cyc slack. The untouched segment
// is pre-exp2: ds_read(~124) -> MFMA0 -> MFMA1 (serial 2-deep) -> exp2.
// Change: K=64 as two INDEPENDENT MFMAs (accA = mfma(a0,B0,ci),
// accB = mfma(a1,B1,0)) that pipeline back-to-back; merge = one packed
// add per gate (~4cyc) replacing the second MFMA's dependent latency
// (~16-32cyc). Saves ~20-30cyc/block-step, x2 multiplexed blocks.
// Pre-commit: if neutral (+-1%), every step segment has been shown
// insensitive and the barrier-multiplex skeleton IS the floor: declare
// 233us structural and stop.
// MFMA layouts (m89-verified): A[m=lane&15][k=(lane>>4)*8+i],
// B[k=(lane>>4)*8+i][n=lane&15], D[m=(lane>>4)*4+r][n=lane&15].

#define TT   512
#define MB   8
#define HP   72            // f16 row stride (144 B): 16B-aligned, 2-way max
#define BUFE (16 * HP)     // one ping-pong buffer: 16 rows
#define SXP  10            // sh_x row stride (floats)

#define L2E  1.4426950408889634f
#define L2E2 2.8853900817779268f

typedef _Float16 f16x8 __attribute__((ext_vector_type(8)));
typedef float    f32x4 __attribute__((ext_vector_type(4)));
typedef float    f32x2 __attribute__((ext_vector_type(2)));

#define MFMA16(a, b, c) __builtin_amdgcn_mfma_f32_16x16x32_f16((a), (b), (c), 0, 0, 0)

__device__ __forceinline__ float rcp_(float x)  { return __builtin_amdgcn_rcpf(x); }
__device__ __forceinline__ float exp2_(float x) { return __builtin_amdgcn_exp2f(x); }

__device__ __forceinline__ f16x8 cvt8s(const float4& u0, const float4& u1, float s) {
    f16x8 r;
    r[0] = (_Float16)(u0.x * s); r[1] = (_Float16)(u0.y * s);
    r[2] = (_Float16)(u0.z * s); r[3] = (_Float16)(u0.w * s);
    r[4] = (_Float16)(u1.x * s); r[5] = (_Float16)(u1.y * s);
    r[6] = (_Float16)(u1.z * s); r[7] = (_Float16)(u1.w * s);
    return r;
}

__global__ __launch_bounds__(256, 2) void lstm_mfma(
    const float* __restrict__ x,      // [4096, 512]
    const float* __restrict__ w_ih,   // [256]
    const float* __restrict__ w_hh,   // [256, 64]
    const float* __restrict__ b_ih,   // [256]
    const float* __restrict__ b_hh,   // [256]
    const float* __restrict__ w_out,  // [64]
    const float* __restrict__ b_out,  // [1]
    float* __restrict__ out)          // [4096]
{
    __shared__ __align__(16) float    sh_x[TT * SXP];   // [t][m], 20 KB
    __shared__ __align__(16) _Float16 hbuf[2 * BUFE];   // 4.6 KB

    const int tid = threadIdx.x;
    const int w   = tid >> 6;    // wave 0..3 (owns N-tiles {w, w+4, w+8, w+12})
    const int L   = tid & 63;
    const int l16 = L & 15;
    const int h0  = L >> 4;      // 0..3
    const int b0  = blockIdx.x * MB;
    const int j   = 16 * w + l16;  // hidden unit col owned by this lane

    // ---- stage x: sh_x[t*SXP + m] = x[b0+m][t] (coalesced) ----
    {
        const int q = tid >> 5;   // batch 0..7
        const int l = tid & 31;
        const float* xr = x + (size_t)(b0 + q) * TT;
        #pragma unroll
        for (int i = 0; i < TT / 32; ++i)
            sh_x[(l + 32 * i) * SXP + q] = xr[l + 32 * i];
    }
    // ---- zero both h buffers (odd rows stay zero forever) ----
    for (int i = tid; i < 2 * BUFE; i += 256) hbuf[i] = (_Float16)0.0f;

    // ---- preload W_hh fragments, exp2-prescaled ----
    const float sc[4] = {-L2E, -L2E, L2E2, -L2E};
    f16x8 Bf[4][2];
    float wihv[4], biasv[4];
    #pragma unroll
    for (int s = 0; s < 4; ++s) {
        const int n = 64 * s + j;
        #pragma unroll
        for (int kt = 0; kt < 2; ++kt) {
            const float* p = w_hh + n * 64 + kt * 32 + h0 * 8;
            float4 u0 = *(const float4*)p;
            float4 u1 = *(const float4*)(p + 4);
            Bf[s][kt] = cvt8s(u0, u1, sc[s]);
        }
        wihv[s]  = w_ih[n] * sc[s];
        biasv[s] = (b_ih[n] + b_hh[n]) * sc[s];
    }

    // lane's A row m=l16: batch l16>>1 if l16 even (odd rows zero)
    const int aoff = l16 * HP + h0 * 8;   // f16 units; +32 for K-chunk 1
    // lane's cells: batches 2h0, 2h0+1 -> h rows 4h0 (cell0), 4h0+2 (cell1)
    const int xoff = 2 * h0;
    const int wr   = 4 * h0 * HP + j;

    f32x2 ccv = {0.0f, 0.0f};   // c-state of the lane's two cells, x2log2e

    // C-operand pipeline: rows 0,2 = x*w_ih+bias for batches 2h0, 2h0+1
    f32x4 ci[4];
    {
        const float2 x0 = *(const float2*)(sh_x + xoff);
        #pragma unroll
        for (int s = 0; s < 4; ++s) {
            ci[s][0] = fmaf(x0.x, wihv[s], biasv[s]);
            ci[s][1] = 0.0f;
            ci[s][2] = fmaf(x0.y, wihv[s], biasv[s]);
            ci[s][3] = 0.0f;
        }
    }

    __syncthreads();

    // ---- phase stagger: desync co-resident blocks by ~half a step ----
    if (((blockIdx.x >> 8) ^ blockIdx.x) & 1) {
        __builtin_amdgcn_s_sleep(10);   // ~640 cyc
    }

    const f32x4 zv = {0.0f, 0.0f, 0.0f, 0.0f};

    auto step = [&](const _Float16* rb, _Float16* wb, int t) {
        f16x8 a0 = *(const f16x8*)(rb + aoff);
        f16x8 a1 = *(const f16x8*)(rb + aoff + 32);

        // K-split: two INDEPENDENT MFMAs per gate (pipeline, no dep chain);
        // merge below with one packed add per gate.
        f32x4 accA[4], accB[4];
        #pragma unroll
        for (int s = 0; s < 4; ++s) {
            accA[s] = MFMA16(a0, Bf[s][0], ci[s]);
            accB[s] = MFMA16(a1, Bf[s][1], zv);
        }

        // refresh ci for t+1 in the MFMA shadow (h-independent, packed fma)
        if (t + 1 < TT) {
            const float2 xn = *(const float2*)(sh_x + (t + 1) * SXP + xoff);
            const f32x2 xnv = {xn.x, xn.y};
            #pragma unroll
            for (int s = 0; s < 4; ++s) {
                f32x2 c2 = xnv * wihv[s] + biasv[s];   // v_pk_fma_f32
                ci[s][0] = c2[0];
                ci[s][2] = c2[1];
            }
        }

        // ---- T5: favor the serial cell-math chain over the co-resident
        // block's staging-phase waves (role diversity via half-step stagger)
        __builtin_amdgcn_s_setprio(1);

        // merge K-halves (v_pk_add_f32) straight into the exp2 args
        f32x2 Si = {accA[0][0] + accB[0][0], accA[0][2] + accB[0][2]};
        f32x2 Sf = {accA[1][0] + accB[1][0], accA[1][2] + accB[1][2]};
        f32x2 Sg = {accA[2][0] + accB[2][0], accA[2][2] + accB[2][2]};
        f32x2 So = {accA[3][0] + accB[3][0], accA[3][2] + accB[3][2]};

        // ---- dual-cell update, direct per-gate reciprocals (short chain) --
        f32x2 Ei = {exp2_(Si[0]), exp2_(Si[1])};
        f32x2 Ef = {exp2_(Sf[0]), exp2_(Sf[1])};
        f32x2 Eg = {exp2_(Sg[0]), exp2_(Sg[1])};
        f32x2 Eo = {exp2_(So[0]), exp2_(So[1])};
        f32x2 Di = Ei + 1.0f, Df = Ef + 1.0f, Dg = Eg + 1.0f, Do = Eo + 1.0f;

        f32x2 si = {rcp_(Di[0]), rcp_(Di[1])};   // sigma(i)
        f32x2 sf = {rcp_(Df[0]), rcp_(Df[1])};   // sigma(f)
        f32x2 rg = {rcp_(Dg[0]), rcp_(Dg[1])};
        f32x2 so = {rcp_(Do[0]), rcp_(Do[1])};   // sigma(o), off-chain early

        f32x2 tgs = (-2.0f * L2E2) * rg + L2E2;  // 2log2e * tanh(g), pk fma
        ccv = sf * ccv + si * tgs;               // scaled c-state update

        f32x2 cc = {fminf(ccv[0], 30.0f), fminf(ccv[1], 30.0f)};
        f32x2 Ec = {exp2_(cc[0]), exp2_(cc[1])};
        f32x2 Dc = Ec + 1.0f;
        f32x2 rc = {rcp_(Dc[0]), rcp_(Dc[1])};
        f32x2 hv = (-2.0f * so) * rc + so;       // sigma(o)*tanh(c), pk fma

        wb[wr]          = (_Float16)hv[0];   // row 4h0   (batch 2h0)
        wb[wr + 2 * HP] = (_Float16)hv[1];   // row 4h0+2 (batch 2h0+1)

        __builtin_amdgcn_s_setprio(0);
        __syncthreads();
    };

    for (int t = 0; t < TT; t += 2) {
        step(hbuf,        hbuf + BUFE, t);      // read buf0, write buf1
        step(hbuf + BUFE, hbuf,        t + 1);  // read buf1, write buf0
    }

    // ---- epilogue: final h in buf0; wave w reduces batches 2w, 2w+1 ----
    const float wo = w_out[L];
    #pragma unroll
    for (int p = 0; p < 2; ++p) {
        const int q = 2 * w + p;
        float v = (float)hbuf[(2 * q) * HP + L] * wo;
        #pragma unroll
        for (int off = 32; off; off >>= 1) v += __shfl_down(v, off);
        if (L == 0) out[b0 + q] = v + b_out[0];
    }
}

extern "C" void kernel_launch(void* const* d_in, const int* in_sizes, int n_in,
                              void* d_out, int out_size, void* d_ws, size_t ws_size,
                              hipStream_t stream) {
    const float* x     = (const float*)d_in[0];
    const float* w_ih  = (const float*)d_in[1];
    const float* w_hh  = (const float*)d_in[2];
    const float* b_ih  = (const float*)d_in[3];
    const float* b_hh  = (const float*)d_in[4];
    const float* w_out = (const float*)d_in[5];
    const float* b_out = (const float*)d_in[6];
    float* out = (float*)d_out;

    lstm_mfma<<<4096 / MB, 256, 0, stream>>>(x, w_ih, w_hh, b_ih, b_hh,
                                             w_out, b_out, out);
}

// Round 7
// 266.198 us; speedup vs baseline: 1.2222x; 1.0130x over previous
//
#include <hip/hip_runtime.h>

// LSTM B=4096, T=512, I=1, H=64, O=1 (fp32 in/out).
// FINAL (round 20 = round-17 kernel, session best: 232 us steady).
// Structure: MB=8, grid=512 (2 blocks/CU), half-step s_sleep stagger,
// setprio(1) around the serial cell-math window (T5: +15%, the session's
// one real win), one barrier/step, ping-pong h buffers.
// Evidence matrix (steady us): partition sweep 1x16=287 / 2x8=233 / 4x4=314
// / wave-local=432,629 / flag-sync=341 / transposed=375 / K-packed=365;
// chain math long/short=233/233; trans load 12/20=233/233; MFMA dep
// chained/split=233/234. Wall/step ~1090cyc is the exchange skeleton
// (barrier-synced cross-wave LDS h round-trip under 2-block multiplex);
// all-to-all h exchange is provably required (every lane's A-frag
// contracts over all 64 units). Neither pipe saturated: latency floor.
// MFMA layouts (m89-verified): A[m=lane&15][k=(lane>>4)*8+i],
// B[k=(lane>>4)*8+i][n=lane&15], D[m=(lane>>4)*4+r][n=lane&15].

#define TT   512
#define MB   8
#define HP   72            // f16 row stride (144 B): 16B-aligned, 2-way max
#define BUFE (16 * HP)     // one ping-pong buffer: 16 rows
#define SXP  10            // sh_x row stride (floats)

#define L2E  1.4426950408889634f
#define L2E2 2.8853900817779268f

typedef _Float16 f16x8 __attribute__((ext_vector_type(8)));
typedef float    f32x4 __attribute__((ext_vector_type(4)));
typedef float    f32x2 __attribute__((ext_vector_type(2)));

#define MFMA16(a, b, c) __builtin_amdgcn_mfma_f32_16x16x32_f16((a), (b), (c), 0, 0, 0)

__device__ __forceinline__ float rcp_(float x)  { return __builtin_amdgcn_rcpf(x); }
__device__ __forceinline__ float exp2_(float x) { return __builtin_amdgcn_exp2f(x); }

__device__ __forceinline__ f16x8 cvt8s(const float4& u0, const float4& u1, float s) {
    f16x8 r;
    r[0] = (_Float16)(u0.x * s); r[1] = (_Float16)(u0.y * s);
    r[2] = (_Float16)(u0.z * s); r[3] = (_Float16)(u0.w * s);
    r[4] = (_Float16)(u1.x * s); r[5] = (_Float16)(u1.y * s);
    r[6] = (_Float16)(u1.z * s); r[7] = (_Float16)(u1.w * s);
    return r;
}

__global__ __launch_bounds__(256, 2) void lstm_mfma(
    const float* __restrict__ x,      // [4096, 512]
    const float* __restrict__ w_ih,   // [256]
    const float* __restrict__ w_hh,   // [256, 64]
    const float* __restrict__ b_ih,   // [256]
    const float* __restrict__ b_hh,   // [256]
    const float* __restrict__ w_out,  // [64]
    const float* __restrict__ b_out,  // [1]
    float* __restrict__ out)          // [4096]
{
    __shared__ __align__(16) float    sh_x[TT * SXP];   // [t][m], 20 KB
    __shared__ __align__(16) _Float16 hbuf[2 * BUFE];   // 4.6 KB

    const int tid = threadIdx.x;
    const int w   = tid >> 6;    // wave 0..3 (owns N-tiles {w, w+4, w+8, w+12})
    const int L   = tid & 63;
    const int l16 = L & 15;
    const int h0  = L >> 4;      // 0..3
    const int b0  = blockIdx.x * MB;
    const int j   = 16 * w + l16;  // hidden unit col owned by this lane

    // ---- stage x: sh_x[t*SXP + m] = x[b0+m][t] (coalesced) ----
    {
        const int q = tid >> 5;   // batch 0..7
        const int l = tid & 31;
        const float* xr = x + (size_t)(b0 + q) * TT;
        #pragma unroll
        for (int i = 0; i < TT / 32; ++i)
            sh_x[(l + 32 * i) * SXP + q] = xr[l + 32 * i];
    }
    // ---- zero both h buffers (odd rows stay zero forever) ----
    for (int i = tid; i < 2 * BUFE; i += 256) hbuf[i] = (_Float16)0.0f;

    // ---- preload W_hh fragments, exp2-prescaled ----
    const float sc[4] = {-L2E, -L2E, L2E2, -L2E};
    f16x8 Bf[4][2];
    float wihv[4], biasv[4];
    #pragma unroll
    for (int s = 0; s < 4; ++s) {
        const int n = 64 * s + j;
        #pragma unroll
        for (int kt = 0; kt < 2; ++kt) {
            const float* p = w_hh + n * 64 + kt * 32 + h0 * 8;
            float4 u0 = *(const float4*)p;
            float4 u1 = *(const float4*)(p + 4);
            Bf[s][kt] = cvt8s(u0, u1, sc[s]);
        }
        wihv[s]  = w_ih[n] * sc[s];
        biasv[s] = (b_ih[n] + b_hh[n]) * sc[s];
    }

    // lane's A row m=l16: batch l16>>1 if l16 even (odd rows zero)
    const int aoff = l16 * HP + h0 * 8;   // f16 units; +32 for K-chunk 1
    // lane's cells: batches 2h0, 2h0+1 -> h rows 4h0 (cell0), 4h0+2 (cell1)
    const int xoff = 2 * h0;
    const int wr   = 4 * h0 * HP + j;

    f32x2 ccv = {0.0f, 0.0f};   // c-state of the lane's two cells, x2log2e

    // C-operand pipeline: rows 0,2 = x*w_ih+bias for batches 2h0, 2h0+1
    f32x4 ci[4];
    {
        const float2 x0 = *(const float2*)(sh_x + xoff);
        #pragma unroll
        for (int s = 0; s < 4; ++s) {
            ci[s][0] = fmaf(x0.x, wihv[s], biasv[s]);
            ci[s][1] = 0.0f;
            ci[s][2] = fmaf(x0.y, wihv[s], biasv[s]);
            ci[s][3] = 0.0f;
        }
    }

    __syncthreads();

    // ---- phase stagger: desync co-resident blocks by ~half a step ----
    if (((blockIdx.x >> 8) ^ blockIdx.x) & 1) {
        __builtin_amdgcn_s_sleep(10);   // ~640 cyc
    }

    auto step = [&](const _Float16* rb, _Float16* wb, int t) {
        f16x8 a0 = *(const f16x8*)(rb + aoff);
        f16x8 a1 = *(const f16x8*)(rb + aoff + 32);

        f32x4 acc[4];
        #pragma unroll
        for (int s = 0; s < 4; ++s)
            acc[s] = MFMA16(a1, Bf[s][1], MFMA16(a0, Bf[s][0], ci[s]));

        // refresh ci for t+1 in the MFMA shadow (h-independent, packed fma)
        if (t + 1 < TT) {
            const float2 xn = *(const float2*)(sh_x + (t + 1) * SXP + xoff);
            const f32x2 xnv = {xn.x, xn.y};
            #pragma unroll
            for (int s = 0; s < 4; ++s) {
                f32x2 c2 = xnv * wihv[s] + biasv[s];   // v_pk_fma_f32
                ci[s][0] = c2[0];
                ci[s][2] = c2[1];
            }
        }

        // ---- T5: favor the serial cell-math chain over the co-resident
        // block's staging-phase waves (role diversity via half-step stagger)
        __builtin_amdgcn_s_setprio(1);

        // ---- dual-cell update, direct per-gate reciprocals (short chain) --
        f32x2 Ei = {exp2_(acc[0][0]), exp2_(acc[0][2])};
        f32x2 Ef = {exp2_(acc[1][0]), exp2_(acc[1][2])};
        f32x2 Eg = {exp2_(acc[2][0]), exp2_(acc[2][2])};
        f32x2 Eo = {exp2_(acc[3][0]), exp2_(acc[3][2])};
        f32x2 Di = Ei + 1.0f, Df = Ef + 1.0f, Dg = Eg + 1.0f, Do = Eo + 1.0f;

        f32x2 si = {rcp_(Di[0]), rcp_(Di[1])};   // sigma(i)
        f32x2 sf = {rcp_(Df[0]), rcp_(Df[1])};   // sigma(f)
        f32x2 rg = {rcp_(Dg[0]), rcp_(Dg[1])};
        f32x2 so = {rcp_(Do[0]), rcp_(Do[1])};   // sigma(o), off-chain early

        f32x2 tgs = (-2.0f * L2E2) * rg + L2E2;  // 2log2e * tanh(g), pk fma
        ccv = sf * ccv + si * tgs;               // scaled c-state update

        f32x2 cc = {fminf(ccv[0], 30.0f), fminf(ccv[1], 30.0f)};
        f32x2 Ec = {exp2_(cc[0]), exp2_(cc[1])};
        f32x2 Dc = Ec + 1.0f;
        f32x2 rc = {rcp_(Dc[0]), rcp_(Dc[1])};
        f32x2 hv = (-2.0f * so) * rc + so;       // sigma(o)*tanh(c), pk fma

        wb[wr]          = (_Float16)hv[0];   // row 4h0   (batch 2h0)
        wb[wr + 2 * HP] = (_Float16)hv[1];   // row 4h0+2 (batch 2h0+1)

        __builtin_amdgcn_s_setprio(0);
        __syncthreads();
    };

    for (int t = 0; t < TT; t += 2) {
        step(hbuf,        hbuf + BUFE, t);      // read buf0, write buf1
        step(hbuf + BUFE, hbuf,        t + 1);  // read buf1, write buf0
    }

    // ---- epilogue: final h in buf0; wave w reduces batches 2w, 2w+1 ----
    const float wo = w_out[L];
    #pragma unroll
    for (int p = 0; p < 2; ++p) {
        const int q = 2 * w + p;
        float v = (float)hbuf[(2 * q) * HP + L] * wo;
        #pragma unroll
        for (int off = 32; off; off >>= 1) v += __shfl_down(v, off);
        if (L == 0) out[b0 + q] = v + b_out[0];
    }
}

extern "C" void kernel_launch(void* const* d_in, const int* in_sizes, int n_in,
                              void* d_out, int out_size, void* d_ws, size_t ws_size,
                              hipStream_t stream) {
    const float* x     = (const float*)d_in[0];
    const float* w_ih  = (const float*)d_in[1];
    const float* w_hh  = (const float*)d_in[2];
    const float* b_ih  = (const float*)d_in[3];
    const float* b_hh  = (const float*)d_in[4];
    const float* w_out = (const float*)d_in[5];
    const float* b_out = (const float*)d_in[6];
    float* out = (float*)d_out;

    lstm_mfma<<<4096 / MB, 256, 0, stream>>>(x, w_ih, w_hh, b_ih, b_hh,
                                             w_out, b_out, out);
}